// Round 17
// baseline (160.467 us; speedup 1.0000x reference)
//
#include <hip/hip_runtime.h>
#include <math.h>

#define HIDN 512
#define PROJ 1024
#define ATTN 128
#define BATCH 4
#define SEQ 2048
#define N1 (2*PROJ+ATTN)      // 2176
#define ROWS (BATCH*SEQ)      // 8192

typedef __attribute__((ext_vector_type(4))) float f32x4;
typedef __attribute__((ext_vector_type(8))) short bf16x8;

// bf16 <-> f32 via bit ops (round-to-nearest-even), no header dependency
__device__ __forceinline__ short f2bf(float x){
    unsigned u = __builtin_bit_cast(unsigned, x);
    unsigned rounding = 0x7fffu + ((u >> 16) & 1u);
    u += rounding;
    return (short)(u >> 16);
}
__device__ __forceinline__ float bf2f(short s){
    unsigned u = ((unsigned)(unsigned short)s) << 16;
    return __builtin_bit_cast(float, u);
}

__device__ __forceinline__ void gload16(const void* g, void* l){
    __builtin_amdgcn_global_load_lds((const __attribute__((address_space(1))) void*)g,
                                     (__attribute__((address_space(3))) void*)l,
                                     16, 0, 0);
}

// ---------------- double-buffered bt-GEMM tile: C[128x128] = A[M][K] @ BT[N][K]^T
// 256 threads (4 waves, 2x2), 16x16x32 bf16 MFMA. T3 minimum-2-phase + T2 swizzle.
template<int BK, class Epi>
__device__ __forceinline__ void gemm_bt_tile(const short* __restrict__ A, int lda,
                                             const short* __restrict__ BT, int ldb,
                                             int m0, int n0, int K, Epi epi)
{
    __shared__ __align__(16) short lA[2][128*BK];
    __shared__ __align__(16) short lB[2][128*BK];
    const int t = threadIdx.x;
    const int lane = t & 63;
    const int w = t >> 6;
    const int wr = (w >> 1) * 64, wc = (w & 1) * 64;
    const int half = lane >> 4, l16 = lane & 15;
    constexpr int SPT = BK/16;            // bf16x8 loads per thread per matrix

    f32x4 acc[4][4];
    #pragma unroll
    for (int i=0;i<4;i++)
        #pragma unroll
        for (int j=0;j<4;j++)
            acc[i][j] = (f32x4){0.f,0.f,0.f,0.f};

    auto stage = [&](int buf, int k0){
        #pragma unroll
        for (int i = 0; i < SPT; i++) {
            int li = i*256 + t;
            int r = li / (BK/8), s = li % (BK/8);
            int ss = (BK==64) ? (s ^ (r & 7)) : (s ^ ((r >> 1) & 3));
            gload16(A + (size_t)(m0+r)*lda + k0 + ss*8, lA[buf] + li*8);
        }
        #pragma unroll
        for (int i = 0; i < SPT; i++) {
            int li = i*256 + t;
            int r = li / (BK/8), s = li % (BK/8);
            int ss = (BK==64) ? (s ^ (r & 7)) : (s ^ ((r >> 1) & 3));
            gload16(BT + (size_t)(n0+r)*ldb + k0 + ss*8, lB[buf] + li*8);
        }
    };

    stage(0, 0);
    __syncthreads();
    int cur = 0;
    for (int k0 = BK; k0 <= K; k0 += BK) {
        if (k0 < K) stage(cur^1, k0);             // prefetch next tile during MFMA
        #pragma unroll
        for (int kk = 0; kk < BK; kk += 32) {
            bf16x8 af[4], bfr[4];
            const int cs = (kk >> 3) + half;
            #pragma unroll
            for (int i=0;i<4;i++){
                int row = wr + i*16 + l16;
                int sl = (BK==64) ? (cs ^ (row & 7)) : (cs ^ ((row >> 1) & 3));
                af[i] = *(const bf16x8*)(lA[cur] + row*BK + sl*8);
            }
            #pragma unroll
            for (int j=0;j<4;j++){
                int row = wc + j*16 + l16;
                int sl = (BK==64) ? (cs ^ (row & 7)) : (cs ^ ((row >> 1) & 3));
                bfr[j] = *(const bf16x8*)(lB[cur] + row*BK + sl*8);
            }
            #pragma unroll
            for (int i=0;i<4;i++)
                #pragma unroll
                for (int j=0;j<4;j++)
                    acc[i][j] = __builtin_amdgcn_mfma_f32_16x16x32_bf16(af[i], bfr[j], acc[i][j], 0, 0, 0);
        }
        __syncthreads();
        cur ^= 1;
    }
    // C/D layout: col = lane&15, row = (lane>>4)*4 + q   [m89/m91 verified]
    #pragma unroll
    for (int i=0;i<4;i++)
        #pragma unroll
        for (int j=0;j<4;j++)
            #pragma unroll
            for (int q=0;q<4;q++)
                epi(m0 + wr + i*16 + half*4 + q, n0 + wc + j*16 + l16, acc[i][j][q]);
}

// ---------------- helpers ----------------
__global__ void k_cast_node(const float* __restrict__ in, short* __restrict__ out){
    int idx = blockIdx.x*256 + threadIdx.x;
    const float4 v = ((const float4*)in)[idx];
    short4 o; o.x = f2bf(v.x); o.y = f2bf(v.y); o.z = f2bf(v.z); o.w = f2bf(v.w);
    ((short4*)out)[idx] = o;
}

__global__ void k_transpose_cast(const float* __restrict__ in, short* __restrict__ out,
                                 int R, int C){
    __shared__ short tile[64][65];
    int r0 = blockIdx.y*64, c0 = blockIdx.x*64;
    int t = threadIdx.x;
    #pragma unroll
    for (int i=0;i<16;i++){
        int lin = i*256 + t; int r = lin>>6, c = lin&63;
        tile[r][c] = f2bf(in[(size_t)(r0+r)*C + c0+c]);
    }
    __syncthreads();
    #pragma unroll
    for (int i=0;i<16;i++){
        int lin = i*256 + t; int c = lin>>6, r = lin&63;
        out[(size_t)(c0+c)*R + r0+r] = tile[r][c];
    }
}

// ---------------- GEMM1 (N=2048): silu(node@w1+b1) -> gates (row-major) / VT (transposed)
// 256x128 tile, BK=32, 512 threads (8 waves 4x2). Epilogue: LDS bounce in two
// 128-row passes; values-tiles written TRANSPOSED in LDS -> direct coalesced VT
// stores (kills k_transpose_v); gates-tiles row-major 16B stores.
__global__ __launch_bounds__(512) void k_mm1(const short* __restrict__ nodeb,
        const short* __restrict__ w1T, const float* __restrict__ b1,
        short* __restrict__ gates, short* __restrict__ VT){
    __shared__ __align__(16) short smem[24576];   // 48KB: lA 16384 sh | lB 8192 sh; bounce overlays
    short* lA = smem;                              // [2][256*32]
    short* lB = smem + 16384;                      // [2][128*32]

    const int b = blockIdx.x;                      // 512 blocks = 8 * 64
    const int wg = (b & 7) * 64 + (b >> 3);        // XCD-chunked
    const int n0 = (wg & 15) * 128;                // 16 n-tiles over N=2048
    const int m0 = (wg >> 4) * 256;                // 32 m-tiles over 8192
    const int t = threadIdx.x;
    const int lane = t & 63;
    const int w = t >> 6;
    const int wr = (w >> 1) * 64, wc = (w & 1) * 64;
    const int half = lane >> 4, l16 = lane & 15;

    f32x4 acc[4][4];
    #pragma unroll
    for (int i=0;i<4;i++)
        #pragma unroll
        for (int j=0;j<4;j++)
            acc[i][j] = (f32x4){0.f,0.f,0.f,0.f};

    auto stage = [&](int buf, int k0){
        #pragma unroll
        for (int i = 0; i < 2; i++) {     // A: 256 rows x 4 slots = 1024 / 512 thr
            int li = i*512 + t;
            int r = li >> 2, s = li & 3;
            int ss = s ^ ((r >> 1) & 3);
            gload16(nodeb + (size_t)(m0+r)*HIDN + k0 + ss*8, lA + buf*8192 + li*8);
        }
        {                                  // B: 128 rows x 4 slots = 512 / 512 thr
            int li = t;
            int r = li >> 2, s = li & 3;
            int ss = s ^ ((r >> 1) & 3);
            gload16(w1T + (size_t)(n0+r)*HIDN + k0 + ss*8, lB + buf*4096 + li*8);
        }
    };

    stage(0, 0);
    __syncthreads();
    int cur = 0;
    for (int k0 = 32; k0 <= HIDN; k0 += 32) {
        if (k0 < HIDN) stage(cur^1, k0);
        {
            bf16x8 af[4], bfr[4];
            const int cs = half;
            #pragma unroll
            for (int i=0;i<4;i++){
                int row = wr + i*16 + l16;
                af[i] = *(const bf16x8*)(lA + cur*8192 + row*32 + (cs ^ ((row >> 1) & 3))*8);
            }
            #pragma unroll
            for (int j=0;j<4;j++){
                int row = wc + j*16 + l16;
                bfr[j] = *(const bf16x8*)(lB + cur*4096 + row*32 + (cs ^ ((row >> 1) & 3))*8);
            }
            #pragma unroll
            for (int i=0;i<4;i++)
                #pragma unroll
                for (int j=0;j<4;j++)
                    acc[i][j] = __builtin_amdgcn_mfma_f32_16x16x32_bf16(af[i], bfr[j], acc[i][j], 0, 0, 0);
        }
        __syncthreads();
        cur ^= 1;
    }

    // ---- epilogue: silu + LDS bounce, two 128-row passes
    const bool isv = (n0 >= PROJ);
    const int z = m0 >> 11, m0b = m0 & (SEQ-1);
    float bcol[4];
    #pragma unroll
    for (int j=0;j<4;j++) bcol[j] = b1[n0 + wc + j*16 + l16];

    #pragma unroll
    for (int p = 0; p < 2; ++p){
        if ((wr >> 7) == p){               // waves whose rows lie in this pass
            const int rbase = wr - p*128;
            #pragma unroll
            for (int i=0;i<4;i++)
                #pragma unroll
                for (int j=0;j<4;j++){
                    const int c = wc + j*16 + l16;
                    #pragma unroll
                    for (int q=0;q<4;q++){
                        int r = rbase + i*16 + half*4 + q;
                        float v = acc[i][j][q] + bcol[j];
                        v = v / (1.f + __expf(-v));
                        short bv = f2bf(v);
                        if (isv) smem[c*136 + r] = bv;   // transposed: [col][row]
                        else     smem[r*136 + c] = bv;   // row-major: [row][col]
                    }
                }
        }
        __syncthreads();
        // coalesced store: 128x128 = 2048 groups of 8 shorts
        #pragma unroll
        for (int it=0; it<4; ++it){
            int idx = it*512 + t;
            int rr = idx >> 4, g = idx & 15;
            bf16x8 v = *(const bf16x8*)(smem + rr*136 + g*8);
            if (isv)   // rr = value-col, g*8 = row offset within pass
                *(bf16x8*)(VT + ((size_t)z*PROJ + (n0 - PROJ) + rr)*SEQ + m0b + p*128 + g*8) = v;
            else       // rr = row, g*8 = col offset
                *(bf16x8*)(gates + (size_t)(m0 + p*128 + rr)*PROJ + n0 + g*8) = v;
        }
        __syncthreads();
    }
}

// ---------------- base-column GEMM: baseb = silu(node @ w1[:,2048:2176] + b1[2048:])
__global__ __launch_bounds__(256) void k_mmbase(const short* __restrict__ nodeb,
        const short* __restrict__ w1T, const float* __restrict__ b1,
        short* __restrict__ baseb){
    int m0 = blockIdx.x * 128;             // 64 blocks; n-tile fixed (128 cols)
    const short* BT = w1T + (size_t)(2*PROJ)*HIDN;
    gemm_bt_tile<32>(nodeb, HIDN, BT, HIDN, m0, 0, HIDN,
        [=](int row, int col, float v){
            v += b1[2*PROJ + col];
            v = v / (1.f + __expf(-v));
            baseb[(size_t)row*ATTN + col] = f2bf(v);
        });
}

// ---------------- RoPE
__global__ void k_rope2(const short* __restrict__ baseb, const float* __restrict__ msw,
                        const float* __restrict__ msb, const float* __restrict__ scaling,
                        short* __restrict__ qb, short* __restrict__ kb){
    int idx = blockIdx.x*256 + threadIdx.x;
    int d = idx & 63;
    int row = idx >> 6;
    int l = row & (SEQ-1);
    float inv = exp2f(-(float)d * (13.287712379549449f/64.f));
    float ang = (float)l * inv;
    float s = sinf(ang), c = cosf(ang);
    const short* bp = baseb + (size_t)row*ATTN;
    float b_lo = bf2f(bp[d]), b_hi = bf2f(bp[d+64]);
    float x1q = b_lo*msw[d]        + msb[d];
    float x2q = b_hi*msw[d+64]     + msb[d+64];
    float x1k = b_lo*msw[128+d]    + msb[128+d];
    float x2k = b_hi*msw[128+d+64] + msb[128+d+64];
    float sc = scaling[0];
    qb[(size_t)row*ATTN + d]    = f2bf((x1q*c - x2q*s)*sc);
    qb[(size_t)row*ATTN + d+64] = f2bf((x2q*c + x1q*s)*sc);
    kb[(size_t)row*ATTN + d]    = f2bf(x1k*c - x2k*s);
    kb[(size_t)row*ATTN + d+64] = f2bf(x2k*c + x1k*s);
}

// ---------------- QK^T + bias + exp -> UNNORMALIZED bf16 P~ + per-kvtile rowsums.
// GEMM-structured [R15-proven]: stage K+Q via swizzled global_load_lds, MFMA
// S^T=K.Q^T seeded by f32x4 bias loads, exp -> LDS transpose -> coalesced stores.
__global__ __launch_bounds__(256) void k_qksm(
        const short* __restrict__ qg, const short* __restrict__ kg,
        const float* __restrict__ bias, short* __restrict__ P,
        float* __restrict__ lsum16)
{
    __shared__ __align__(16) short smem[32768];    // 64KB: K(16K sh) | Q(16K sh); pt overlays
    __shared__ float sl[2][128];

    const int b = blockIdx.x;
    const int wg = (b & 7) * 128 + (b >> 3);       // XCD-chunked swizzle (1024 = 8*128)
    const int z  = wg >> 8;
    const int qt = (wg >> 4) & 15;
    const int kt = wg & 15;
    const int q0 = qt * 128, kv0 = kt * 128;

    const int t = threadIdx.x;
    const int lane = t & 63, w = t >> 6;
    const int wr = (w >> 1)*64, wc = (w & 1)*64;
    const int half = lane >> 4, l16 = lane & 15;

    const short* Kg = kg + ((size_t)z*SEQ + kv0)*ATTN;
    const short* Qg = qg + ((size_t)z*SEQ + q0)*ATTN;

    // stage K-tile -> smem[0:16384], Q-tile -> smem[16384:32768]; swizzle slot^(r&15)
    #pragma unroll
    for (int i = 0; i < 8; i++) {
        int li = i*256 + t;            // 0..2047
        int r = li >> 4, s = li & 15;
        int ss = s ^ (r & 15);
        gload16(Kg + (size_t)r*ATTN + ss*8, smem + li*8);
        gload16(Qg + (size_t)r*ATTN + ss*8, smem + 16384 + li*8);
    }

    // acc seeded by bias: acc[i][j] = bias[q0+col][kv0+row .. +3]  (f32x4)
    f32x4 acc[4][4];
    #pragma unroll
    for (int i=0;i<4;i++)
        #pragma unroll
        for (int j=0;j<4;j++)
            acc[i][j] = *(const f32x4*)(bias
                + ((size_t)z*SEQ + q0 + wc + j*16 + l16)*SEQ
                + kv0 + wr + i*16 + half*4);

    __syncthreads();                   // staging complete

    #pragma unroll
    for (int kk = 0; kk < 128; kk += 32) {
        const int cs = (kk >> 3) + half;
        bf16x8 af[4], bfr[4];
        #pragma unroll
        for (int i=0;i<4;i++){
            int row = wr + i*16 + l16;
            af[i] = *(const bf16x8*)(smem + row*128 + (cs ^ (row & 15))*8);
        }
        #pragma unroll
        for (int j=0;j<4;j++){
            int row = wc + j*16 + l16;
            bfr[j] = *(const bf16x8*)(smem + 16384 + row*128 + (cs ^ (row & 15))*8);
        }
        #pragma unroll
        for (int i=0;i<4;i++)
            #pragma unroll
            for (int j=0;j<4;j++)
                acc[i][j] = __builtin_amdgcn_mfma_f32_16x16x32_bf16(af[i], bfr[j], acc[i][j], 0, 0, 0);
    }

    __syncthreads();                   // all ds_reads done; smem reusable as pt

    // exp + transpose into pt[q][kv] (stride 136 shorts, 8B-aligned writes)
    short* pt = smem;                  // [128][136] = 17408 shorts, fits 32768
    float tsum[4];
    #pragma unroll
    for (int j=0;j<4;j++){
        int col = wc + j*16 + l16;     // q local
        float sj = 0.f;
        #pragma unroll
        for (int i=0;i<4;i++){
            float p0=__expf(acc[i][j][0]), p1=__expf(acc[i][j][1]);
            float p2=__expf(acc[i][j][2]), p3=__expf(acc[i][j][3]);
            sj += p0+p1+p2+p3;
            short4 pv; pv.x=f2bf(p0); pv.y=f2bf(p1); pv.z=f2bf(p2); pv.w=f2bf(p3);
            *(short4*)(pt + col*136 + wr + i*16 + half*4) = pv;   // 8B write, 4 consec kv
        }
        tsum[j] = sj;
    }
    // reduce rows over half-groups -> per-(wave,col) 64-kv sums
    #pragma unroll
    for (int j=0;j<4;j++){
        tsum[j] += __shfl_xor(tsum[j],16,64);
        tsum[j] += __shfl_xor(tsum[j],32,64);
    }
    if (half==0){
        #pragma unroll
        for (int j=0;j<4;j++) sl[wr>>6][wc + j*16 + l16] = tsum[j];
    }
    __syncthreads();

    // coalesced P~ store: 2048 stores = 128 q x 16 groups of 8 bf16
    short* Pp = P + ((size_t)z*SEQ + q0)*SEQ + kv0;
    #pragma unroll
    for (int i=0;i<8;i++){
        int idx = i*256 + t;           // 0..2047
        int q = idx >> 4, g = idx & 15;
        *(bf16x8*)(Pp + (size_t)q*SEQ + g*8) = *(const bf16x8*)(pt + q*136 + g*8);
    }
    if (t < 128)
        lsum16[(size_t)kt*ROWS + (size_t)z*SEQ + q0 + t] = sl[0][t] + sl[1][t];
}

// ---------------- combine per-kvtile partials -> 1/rowsum
__global__ void k_combine(const float* __restrict__ lsum16, float* __restrict__ linv){
    int r = blockIdx.x*256 + threadIdx.x;
    float s = 0.f;
    #pragma unroll
    for (int kt=0; kt<16; kt++) s += lsum16[(size_t)kt*ROWS + r];
    linv[r] = 1.f/s;
}

// ---------------- PV: a2 = (P~ @ V) * linv * gates  (bf16 out), BK=64
__global__ __launch_bounds__(256) void k_pv2(const short* __restrict__ P,
        const short* __restrict__ VT, const short* __restrict__ gates,
        const float* __restrict__ linv, short* __restrict__ a2){
    int b = blockIdx.x;
    int wg = (b & 7) * 64 + (b >> 3);
    int xx = wg & 7, yy = (wg >> 3) & 15, z = wg >> 7;
    const short* A = P  + (size_t)z*SEQ*SEQ;
    const short* B = VT + (size_t)z*PROJ*SEQ;
    int n0 = xx*128, m0 = yy*128;
    gemm_bt_tile<64>(A, SEQ, B, SEQ, m0, n0, SEQ,
        [=](int r, int c, float v){
            size_t ri = (size_t)z*SEQ + r;
            size_t gi = ri*PROJ + c;
            a2[gi] = f2bf(v * linv[ri] * bf2f(gates[gi]));
        });
}

// ---------------- GEMM2: out = a2 @ w2 + b2  (f32 out), BK=32
__global__ __launch_bounds__(256) void k_mm2(const short* __restrict__ a2,
        const short* __restrict__ w2T, const float* __restrict__ b2,
        float* __restrict__ out){
    int b = blockIdx.x;
    int wg = (b & 7) * 32 + (b >> 3);
    int n0 = (wg & 3)*128, m0 = (wg >> 2)*128;
    gemm_bt_tile<32>(a2, PROJ, w2T, PROJ, m0, n0, PROJ,
        [=](int r, int c, float v){
            out[(size_t)r*HIDN + c] = v + b2[c];
        });
}

extern "C" void kernel_launch(void* const* d_in, const int* in_sizes, int n_in,
                              void* d_out, int out_size, void* d_ws, size_t ws_size,
                              hipStream_t stream) {
    const float* node    = (const float*)d_in[0];
    const float* bias    = (const float*)d_in[1];
    const float* scaling = (const float*)d_in[2];
    const float* w1      = (const float*)d_in[3];
    const float* b1      = (const float*)d_in[4];
    const float* msw     = (const float*)d_in[5];
    const float* msb     = (const float*)d_in[6];
    const float* w2      = (const float*)d_in[7];
    const float* b2      = (const float*)d_in[8];
    float* out = (float*)d_out;

    char* p = (char*)d_ws;
    auto alloc = [&](size_t bytes){ char* r = p; p += (bytes + 255) & ~(size_t)255; return r; };
    short* nodeb  = (short*)alloc((size_t)ROWS*HIDN*2);
    short* w1T    = (short*)alloc((size_t)N1*HIDN*2);
    short* w2T    = (short*)alloc((size_t)HIDN*PROJ*2);
    short* gates  = (short*)alloc((size_t)ROWS*PROJ*2);
    short* VT     = (short*)alloc((size_t)BATCH*PROJ*SEQ*2);
    short* baseb  = (short*)alloc((size_t)ROWS*ATTN*2);
    short* qb     = (short*)alloc((size_t)ROWS*ATTN*2);
    short* kb     = (short*)alloc((size_t)ROWS*ATTN*2);
    short* Pbuf   = (short*)alloc((size_t)BATCH*SEQ*SEQ*2);
    float* lsum16 = (float*)alloc((size_t)16*ROWS*4);
    float* linv   = (float*)alloc((size_t)ROWS*4);
    short* a2buf  = (short*)alloc((size_t)ROWS*PROJ*2);

    k_cast_node<<<ROWS*HIDN/1024, 256, 0, stream>>>(node, nodeb);
    k_transpose_cast<<<dim3(N1/64, HIDN/64), 256, 0, stream>>>(w1, w1T, HIDN, N1);
    k_transpose_cast<<<dim3(HIDN/64, PROJ/64), 256, 0, stream>>>(w2, w2T, PROJ, HIDN);
    // 1) gva = silu(node@w1+b1): gates row-major + values DIRECT to VT (transposed)
    k_mm1<<<16*(ROWS/256), 512, 0, stream>>>(nodeb, w1T, b1, gates, VT);
    k_mmbase<<<ROWS/128, 256, 0, stream>>>(nodeb, w1T, b1, baseb);
    // 2) rope
    k_rope2<<<ROWS*64/256, 256, 0, stream>>>(baseb, msw, msb, scaling, qb, kb);
    // 3) GEMM-structured qk^T + bias + exp -> P~ + per-kvtile partial sums
    k_qksm<<<16*16*BATCH, 256, 0, stream>>>(qb, kb, bias, Pbuf, lsum16);
    k_combine<<<ROWS/256, 256, 0, stream>>>(lsum16, linv);
    // 3c) a2 = (P~@V)*linv*gates
    k_pv2<<<(PROJ/128)*(SEQ/128)*BATCH, 256, 0, stream>>>(Pbuf, VT, gates, linv, a2buf);
    // 4) out = a2@w2 + b2
    k_mm2<<<(HIDN/128)*(ROWS/128), 256, 0, stream>>>(a2buf, w2T, b2, out);
}

// Round 18
// 156.244 us; speedup vs baseline: 1.0270x; 1.0270x over previous
//
#include <hip/hip_runtime.h>
#include <math.h>

#define HIDN 512
#define PROJ 1024
#define ATTN 128
#define BATCH 4
#define SEQ 2048
#define N1 (2*PROJ+ATTN)      // 2176
#define ROWS (BATCH*SEQ)      // 8192

typedef __attribute__((ext_vector_type(4))) float f32x4;
typedef __attribute__((ext_vector_type(8))) short bf16x8;

// bf16 <-> f32 via bit ops (round-to-nearest-even), no header dependency
__device__ __forceinline__ short f2bf(float x){
    unsigned u = __builtin_bit_cast(unsigned, x);
    unsigned rounding = 0x7fffu + ((u >> 16) & 1u);
    u += rounding;
    return (short)(u >> 16);
}
__device__ __forceinline__ float bf2f(short s){
    unsigned u = ((unsigned)(unsigned short)s) << 16;
    return __builtin_bit_cast(float, u);
}

__device__ __forceinline__ void gload16(const void* g, void* l){
    __builtin_amdgcn_global_load_lds((const __attribute__((address_space(1))) void*)g,
                                     (__attribute__((address_space(3))) void*)l,
                                     16, 0, 0);
}

// ---------------- double-buffered bt-GEMM tile: C[128x128] = A[M][K] @ BT[N][K]^T
// 256 threads (4 waves, 2x2), 16x16x32 bf16 MFMA. T3 minimum-2-phase + T2 swizzle.
// BK=64 = the proven 782TF structure (pv2); BK=32 for short-K/occupancy cases.
template<int BK, class Epi>
__device__ __forceinline__ void gemm_bt_tile(const short* __restrict__ A, int lda,
                                             const short* __restrict__ BT, int ldb,
                                             int m0, int n0, int K, Epi epi)
{
    __shared__ __align__(16) short lA[2][128*BK];
    __shared__ __align__(16) short lB[2][128*BK];
    const int t = threadIdx.x;
    const int lane = t & 63;
    const int w = t >> 6;
    const int wr = (w >> 1) * 64, wc = (w & 1) * 64;
    const int half = lane >> 4, l16 = lane & 15;
    constexpr int SPT = BK/16;            // bf16x8 loads per thread per matrix

    f32x4 acc[4][4];
    #pragma unroll
    for (int i=0;i<4;i++)
        #pragma unroll
        for (int j=0;j<4;j++)
            acc[i][j] = (f32x4){0.f,0.f,0.f,0.f};

    auto stage = [&](int buf, int k0){
        #pragma unroll
        for (int i = 0; i < SPT; i++) {
            int li = i*256 + t;
            int r = li / (BK/8), s = li % (BK/8);
            int ss = (BK==64) ? (s ^ (r & 7)) : (s ^ ((r >> 1) & 3));
            gload16(A + (size_t)(m0+r)*lda + k0 + ss*8, lA[buf] + li*8);
        }
        #pragma unroll
        for (int i = 0; i < SPT; i++) {
            int li = i*256 + t;
            int r = li / (BK/8), s = li % (BK/8);
            int ss = (BK==64) ? (s ^ (r & 7)) : (s ^ ((r >> 1) & 3));
            gload16(BT + (size_t)(n0+r)*ldb + k0 + ss*8, lB[buf] + li*8);
        }
    };

    stage(0, 0);
    __syncthreads();
    int cur = 0;
    for (int k0 = BK; k0 <= K; k0 += BK) {
        if (k0 < K) stage(cur^1, k0);             // prefetch next tile during MFMA
        #pragma unroll
        for (int kk = 0; kk < BK; kk += 32) {
            bf16x8 af[4], bfr[4];
            const int cs = (kk >> 3) + half;
            #pragma unroll
            for (int i=0;i<4;i++){
                int row = wr + i*16 + l16;
                int sl = (BK==64) ? (cs ^ (row & 7)) : (cs ^ ((row >> 1) & 3));
                af[i] = *(const bf16x8*)(lA[cur] + row*BK + sl*8);
            }
            #pragma unroll
            for (int j=0;j<4;j++){
                int row = wc + j*16 + l16;
                int sl = (BK==64) ? (cs ^ (row & 7)) : (cs ^ ((row >> 1) & 3));
                bfr[j] = *(const bf16x8*)(lB[cur] + row*BK + sl*8);
            }
            #pragma unroll
            for (int i=0;i<4;i++)
                #pragma unroll
                for (int j=0;j<4;j++)
                    acc[i][j] = __builtin_amdgcn_mfma_f32_16x16x32_bf16(af[i], bfr[j], acc[i][j], 0, 0, 0);
        }
        __syncthreads();
        cur ^= 1;
    }
    // C/D layout: col = lane&15, row = (lane>>4)*4 + q   [m89/m91 verified]
    #pragma unroll
    for (int i=0;i<4;i++)
        #pragma unroll
        for (int j=0;j<4;j++)
            #pragma unroll
            for (int q=0;q<4;q++)
                epi(m0 + wr + i*16 + half*4 + q, n0 + wc + j*16 + l16, acc[i][j][q]);
}

// ---------------- helpers ----------------
__global__ void k_cast_node(const float* __restrict__ in, short* __restrict__ out){
    int idx = blockIdx.x*256 + threadIdx.x;
    const float4 v = ((const float4*)in)[idx];
    short4 o; o.x = f2bf(v.x); o.y = f2bf(v.y); o.z = f2bf(v.z); o.w = f2bf(v.w);
    ((short4*)out)[idx] = o;
}

__global__ void k_transpose_cast(const float* __restrict__ in, short* __restrict__ out,
                                 int R, int C){
    __shared__ short tile[64][65];
    int r0 = blockIdx.y*64, c0 = blockIdx.x*64;
    int t = threadIdx.x;
    #pragma unroll
    for (int i=0;i<16;i++){
        int lin = i*256 + t; int r = lin>>6, c = lin&63;
        tile[r][c] = f2bf(in[(size_t)(r0+r)*C + c0+c]);
    }
    __syncthreads();
    #pragma unroll
    for (int i=0;i<16;i++){
        int lin = i*256 + t; int c = lin>>6, r = lin&63;
        out[(size_t)(c0+c)*R + r0+r] = tile[r][c];
    }
}

__global__ void k_transpose_v(const short* __restrict__ values, short* __restrict__ VT){
    __shared__ short tile[64][65];
    int z = blockIdx.z;
    int c0 = blockIdx.x*64, r0 = blockIdx.y*64;
    int t = threadIdx.x;
    #pragma unroll
    for (int i=0;i<16;i++){
        int lin = i*256 + t; int r = lin>>6, c = lin&63;
        tile[r][c] = values[(size_t)(z*SEQ + r0+r)*PROJ + c0+c];
    }
    __syncthreads();
    #pragma unroll
    for (int i=0;i<16;i++){
        int lin = i*256 + t; int c = lin>>6, r = lin&63;
        VT[((size_t)z*PROJ + c0+c)*SEQ + r0+r] = tile[r][c];
    }
}

// ---------------- GEMM1 (N=2048): silu(node@w1+b1) -> gates / values
// 128x128 tile, BK=64 (the 782TF pv2 template), pointer-select epilogue.
__global__ __launch_bounds__(256) void k_mm1(const short* __restrict__ nodeb,
        const short* __restrict__ w1T, const float* __restrict__ b1,
        short* __restrict__ gates, short* __restrict__ values){
    int b = blockIdx.x;                    // 1024 blocks = 8 * 128
    int wg = (b & 7) * 128 + (b >> 3);     // XCD-chunked
    int n0 = (wg & 15) * 128;              // 16 n-tiles over N=2048
    int m0 = (wg >> 4) * 128;              // 64 m-tiles over 8192
    short* dst = (n0 < PROJ) ? gates : values;
    const int coff = (n0 < PROJ) ? 0 : PROJ;
    gemm_bt_tile<64>(nodeb, HIDN, w1T, HIDN, m0, n0, HIDN,
        [=](int row, int col, float v){
            v += b1[col];
            v = v / (1.f + __expf(-v));
            dst[(size_t)row*PROJ + (col - coff)] = f2bf(v);
        });
}

// ---------------- base-column GEMM: baseb = silu(node @ w1[:,2048:2176] + b1[2048:])
__global__ __launch_bounds__(256) void k_mmbase(const short* __restrict__ nodeb,
        const short* __restrict__ w1T, const float* __restrict__ b1,
        short* __restrict__ baseb){
    int m0 = blockIdx.x * 128;             // 64 blocks; n-tile fixed (128 cols)
    const short* BT = w1T + (size_t)(2*PROJ)*HIDN;
    gemm_bt_tile<32>(nodeb, HIDN, BT, HIDN, m0, 0, HIDN,
        [=](int row, int col, float v){
            v += b1[2*PROJ + col];
            v = v / (1.f + __expf(-v));
            baseb[(size_t)row*ATTN + col] = f2bf(v);
        });
}

// ---------------- RoPE
__global__ void k_rope2(const short* __restrict__ baseb, const float* __restrict__ msw,
                        const float* __restrict__ msb, const float* __restrict__ scaling,
                        short* __restrict__ qb, short* __restrict__ kb){
    int idx = blockIdx.x*256 + threadIdx.x;
    int d = idx & 63;
    int row = idx >> 6;
    int l = row & (SEQ-1);
    float inv = exp2f(-(float)d * (13.287712379549449f/64.f));
    float ang = (float)l * inv;
    float s = sinf(ang), c = cosf(ang);
    const short* bp = baseb + (size_t)row*ATTN;
    float b_lo = bf2f(bp[d]), b_hi = bf2f(bp[d+64]);
    float x1q = b_lo*msw[d]        + msb[d];
    float x2q = b_hi*msw[d+64]     + msb[d+64];
    float x1k = b_lo*msw[128+d]    + msb[128+d];
    float x2k = b_hi*msw[128+d+64] + msb[128+d+64];
    float sc = scaling[0];
    qb[(size_t)row*ATTN + d]    = f2bf((x1q*c - x2q*s)*sc);
    qb[(size_t)row*ATTN + d+64] = f2bf((x2q*c + x1q*s)*sc);
    kb[(size_t)row*ATTN + d]    = f2bf(x1k*c - x2k*s);
    kb[(size_t)row*ATTN + d+64] = f2bf(x2k*c + x1k*s);
}

// ---------------- QK^T + bias + exp -> UNNORMALIZED bf16 P~ + per-kvtile rowsums.
// GEMM-structured [R15-proven]: stage K+Q via swizzled global_load_lds, MFMA
// S^T=K.Q^T seeded by f32x4 bias loads, exp -> LDS transpose -> coalesced stores.
__global__ __launch_bounds__(256) void k_qksm(
        const short* __restrict__ qg, const short* __restrict__ kg,
        const float* __restrict__ bias, short* __restrict__ P,
        float* __restrict__ lsum16)
{
    __shared__ __align__(16) short smem[32768];    // 64KB: K(16K sh) | Q(16K sh); pt overlays
    __shared__ float sl[2][128];

    const int b = blockIdx.x;
    const int wg = (b & 7) * 128 + (b >> 3);       // XCD-chunked swizzle (1024 = 8*128)
    const int z  = wg >> 8;
    const int qt = (wg >> 4) & 15;
    const int kt = wg & 15;
    const int q0 = qt * 128, kv0 = kt * 128;

    const int t = threadIdx.x;
    const int lane = t & 63, w = t >> 6;
    const int wr = (w >> 1)*64, wc = (w & 1)*64;
    const int half = lane >> 4, l16 = lane & 15;

    const short* Kg = kg + ((size_t)z*SEQ + kv0)*ATTN;
    const short* Qg = qg + ((size_t)z*SEQ + q0)*ATTN;

    // stage K-tile -> smem[0:16384], Q-tile -> smem[16384:32768]; swizzle slot^(r&15)
    #pragma unroll
    for (int i = 0; i < 8; i++) {
        int li = i*256 + t;            // 0..2047
        int r = li >> 4, s = li & 15;
        int ss = s ^ (r & 15);
        gload16(Kg + (size_t)r*ATTN + ss*8, smem + li*8);
        gload16(Qg + (size_t)r*ATTN + ss*8, smem + 16384 + li*8);
    }

    // acc seeded by bias: acc[i][j] = bias[q0+col][kv0+row .. +3]  (f32x4)
    f32x4 acc[4][4];
    #pragma unroll
    for (int i=0;i<4;i++)
        #pragma unroll
        for (int j=0;j<4;j++)
            acc[i][j] = *(const f32x4*)(bias
                + ((size_t)z*SEQ + q0 + wc + j*16 + l16)*SEQ
                + kv0 + wr + i*16 + half*4);

    __syncthreads();                   // staging complete

    #pragma unroll
    for (int kk = 0; kk < 128; kk += 32) {
        const int cs = (kk >> 3) + half;
        bf16x8 af[4], bfr[4];
        #pragma unroll
        for (int i=0;i<4;i++){
            int row = wr + i*16 + l16;
            af[i] = *(const bf16x8*)(smem + row*128 + (cs ^ (row & 15))*8);
        }
        #pragma unroll
        for (int j=0;j<4;j++){
            int row = wc + j*16 + l16;
            bfr[j] = *(const bf16x8*)(smem + 16384 + row*128 + (cs ^ (row & 15))*8);
        }
        #pragma unroll
        for (int i=0;i<4;i++)
            #pragma unroll
            for (int j=0;j<4;j++)
                acc[i][j] = __builtin_amdgcn_mfma_f32_16x16x32_bf16(af[i], bfr[j], acc[i][j], 0, 0, 0);
    }

    __syncthreads();                   // all ds_reads done; smem reusable as pt

    // exp + transpose into pt[q][kv] (stride 136 shorts, 8B-aligned writes)
    short* pt = smem;                  // [128][136] = 17408 shorts, fits 32768
    float tsum[4];
    #pragma unroll
    for (int j=0;j<4;j++){
        int col = wc + j*16 + l16;     // q local
        float sj = 0.f;
        #pragma unroll
        for (int i=0;i<4;i++){
            float p0=__expf(acc[i][j][0]), p1=__expf(acc[i][j][1]);
            float p2=__expf(acc[i][j][2]), p3=__expf(acc[i][j][3]);
            sj += p0+p1+p2+p3;
            short4 pv; pv.x=f2bf(p0); pv.y=f2bf(p1); pv.z=f2bf(p2); pv.w=f2bf(p3);
            *(short4*)(pt + col*136 + wr + i*16 + half*4) = pv;   // 8B write, 4 consec kv
        }
        tsum[j] = sj;
    }
    // reduce rows over half-groups -> per-(wave,col) 64-kv sums
    #pragma unroll
    for (int j=0;j<4;j++){
        tsum[j] += __shfl_xor(tsum[j],16,64);
        tsum[j] += __shfl_xor(tsum[j],32,64);
    }
    if (half==0){
        #pragma unroll
        for (int j=0;j<4;j++) sl[wr>>6][wc + j*16 + l16] = tsum[j];
    }
    __syncthreads();

    // coalesced P~ store: 2048 stores = 128 q x 16 groups of 8 bf16
    short* Pp = P + ((size_t)z*SEQ + q0)*SEQ + kv0;
    #pragma unroll
    for (int i=0;i<8;i++){
        int idx = i*256 + t;           // 0..2047
        int q = idx >> 4, g = idx & 15;
        *(bf16x8*)(Pp + (size_t)q*SEQ + g*8) = *(const bf16x8*)(pt + q*136 + g*8);
    }
    if (t < 128)
        lsum16[(size_t)kt*ROWS + (size_t)z*SEQ + q0 + t] = sl[0][t] + sl[1][t];
}

// ---------------- combine per-kvtile partials -> 1/rowsum
__global__ void k_combine(const float* __restrict__ lsum16, float* __restrict__ linv){
    int r = blockIdx.x*256 + threadIdx.x;
    float s = 0.f;
    #pragma unroll
    for (int kt=0; kt<16; kt++) s += lsum16[(size_t)kt*ROWS + r];
    linv[r] = 1.f/s;
}

// ---------------- PV: a2 = (P~ @ V) * linv * gates  (bf16 out), BK=64
__global__ __launch_bounds__(256) void k_pv2(const short* __restrict__ P,
        const short* __restrict__ VT, const short* __restrict__ gates,
        const float* __restrict__ linv, short* __restrict__ a2){
    int b = blockIdx.x;
    int wg = (b & 7) * 64 + (b >> 3);
    int xx = wg & 7, yy = (wg >> 3) & 15, z = wg >> 7;
    const short* A = P  + (size_t)z*SEQ*SEQ;
    const short* B = VT + (size_t)z*PROJ*SEQ;
    int n0 = xx*128, m0 = yy*128;
    gemm_bt_tile<64>(A, SEQ, B, SEQ, m0, n0, SEQ,
        [=](int r, int c, float v){
            size_t ri = (size_t)z*SEQ + r;
            size_t gi = ri*PROJ + c;
            a2[gi] = f2bf(v * linv[ri] * bf2f(gates[gi]));
        });
}

// ---------------- GEMM2: out = a2 @ w2 + b2  (f32 out), BK=64
__global__ __launch_bounds__(256) void k_mm2(const short* __restrict__ a2,
        const short* __restrict__ w2T, const float* __restrict__ b2,
        float* __restrict__ out){
    int b = blockIdx.x;
    int wg = (b & 7) * 32 + (b >> 3);
    int n0 = (wg & 3)*128, m0 = (wg >> 2)*128;
    gemm_bt_tile<64>(a2, PROJ, w2T, PROJ, m0, n0, PROJ,
        [=](int r, int c, float v){
            out[(size_t)r*HIDN + c] = v + b2[c];
        });
}

extern "C" void kernel_launch(void* const* d_in, const int* in_sizes, int n_in,
                              void* d_out, int out_size, void* d_ws, size_t ws_size,
                              hipStream_t stream) {
    const float* node    = (const float*)d_in[0];
    const float* bias    = (const float*)d_in[1];
    const float* scaling = (const float*)d_in[2];
    const float* w1      = (const float*)d_in[3];
    const float* b1      = (const float*)d_in[4];
    const float* msw     = (const float*)d_in[5];
    const float* msb     = (const float*)d_in[6];
    const float* w2      = (const float*)d_in[7];
    const float* b2      = (const float*)d_in[8];
    float* out = (float*)d_out;

    char* p = (char*)d_ws;
    auto alloc = [&](size_t bytes){ char* r = p; p += (bytes + 255) & ~(size_t)255; return r; };
    short* nodeb  = (short*)alloc((size_t)ROWS*HIDN*2);
    short* w1T    = (short*)alloc((size_t)N1*HIDN*2);
    short* w2T    = (short*)alloc((size_t)HIDN*PROJ*2);
    short* gates  = (short*)alloc((size_t)ROWS*PROJ*2);
    short* values = (short*)alloc((size_t)ROWS*PROJ*2);
    short* VT     = (short*)alloc((size_t)BATCH*PROJ*SEQ*2);
    short* baseb  = (short*)alloc((size_t)ROWS*ATTN*2);
    short* qb     = (short*)alloc((size_t)ROWS*ATTN*2);
    short* kb     = (short*)alloc((size_t)ROWS*ATTN*2);
    short* Pbuf   = (short*)alloc((size_t)BATCH*SEQ*SEQ*2);
    float* lsum16 = (float*)alloc((size_t)16*ROWS*4);
    float* linv   = (float*)alloc((size_t)ROWS*4);
    short* a2buf  = (short*)alloc((size_t)ROWS*PROJ*2);

    k_cast_node<<<ROWS*HIDN/1024, 256, 0, stream>>>(node, nodeb);
    k_transpose_cast<<<dim3(N1/64, HIDN/64), 256, 0, stream>>>(w1, w1T, HIDN, N1);
    k_transpose_cast<<<dim3(HIDN/64, PROJ/64), 256, 0, stream>>>(w2, w2T, PROJ, HIDN);
    // 1) gva = silu(node@w1+b1): N=2048 main GEMM (128², BK=64) + base columns
    k_mm1<<<16*(ROWS/128), 256, 0, stream>>>(nodeb, w1T, b1, gates, values);
    k_mmbase<<<ROWS/128, 256, 0, stream>>>(nodeb, w1T, b1, baseb);
    // transpose values for PV B^T layout
    k_transpose_v<<<dim3(PROJ/64, SEQ/64, BATCH), 256, 0, stream>>>(values, VT);
    // 2) rope
    k_rope2<<<ROWS*64/256, 256, 0, stream>>>(baseb, msw, msb, scaling, qb, kb);
    // 3) GEMM-structured qk^T + bias + exp -> P~ + per-kvtile partial sums
    k_qksm<<<16*16*BATCH, 256, 0, stream>>>(qb, kb, bias, Pbuf, lsum16);
    k_combine<<<ROWS/256, 256, 0, stream>>>(lsum16, linv);
    // 3c) a2 = (P~@V)*linv*gates
    k_pv2<<<(PROJ/128)*(SEQ/128)*BATCH, 256, 0, stream>>>(Pbuf, VT, gates, linv, a2buf);
    // 4) out = a2@w2 + b2
    k_mm2<<<(HIDN/128)*(ROWS/128), 256, 0, stream>>>(a2buf, w2T, b2, out);
}

// Round 19
// 145.934 us; speedup vs baseline: 1.0996x; 1.0706x over previous
//
#include <hip/hip_runtime.h>
#include <math.h>

#define HIDN 512
#define PROJ 1024
#define ATTN 128
#define BATCH 4
#define SEQ 2048
#define N1 (2*PROJ+ATTN)      // 2176
#define ROWS (BATCH*SEQ)      // 8192

typedef __attribute__((ext_vector_type(4))) float f32x4;
typedef __attribute__((ext_vector_type(8))) short bf16x8;

// bf16 <-> f32 via bit ops (round-to-nearest-even), no header dependency
__device__ __forceinline__ short f2bf(float x){
    unsigned u = __builtin_bit_cast(unsigned, x);
    unsigned rounding = 0x7fffu + ((u >> 16) & 1u);
    u += rounding;
    return (short)(u >> 16);
}
__device__ __forceinline__ float bf2f(short s){
    unsigned u = ((unsigned)(unsigned short)s) << 16;
    return __builtin_bit_cast(float, u);
}

__device__ __forceinline__ void gload16(const void* g, void* l){
    __builtin_amdgcn_global_load_lds((const __attribute__((address_space(1))) void*)g,
                                     (__attribute__((address_space(3))) void*)l,
                                     16, 0, 0);
}

// ---------------- double-buffered bt-GEMM tile: C[128x128] = A[M][K] @ BT[N][K]^T
// 256 threads (4 waves, 2x2), 16x16x32 bf16 MFMA. T3 minimum-2-phase + T2 swizzle.
// BK=64 for long-K (pv2/mm2: 782TF); BK=32 for short-K/occupancy cases.
template<int BK, class Epi>
__device__ __forceinline__ void gemm_bt_tile(const short* __restrict__ A, int lda,
                                             const short* __restrict__ BT, int ldb,
                                             int m0, int n0, int K, Epi epi)
{
    __shared__ __align__(16) short lA[2][128*BK];
    __shared__ __align__(16) short lB[2][128*BK];
    const int t = threadIdx.x;
    const int lane = t & 63;
    const int w = t >> 6;
    const int wr = (w >> 1) * 64, wc = (w & 1) * 64;
    const int half = lane >> 4, l16 = lane & 15;
    constexpr int SPT = BK/16;            // bf16x8 loads per thread per matrix

    f32x4 acc[4][4];
    #pragma unroll
    for (int i=0;i<4;i++)
        #pragma unroll
        for (int j=0;j<4;j++)
            acc[i][j] = (f32x4){0.f,0.f,0.f,0.f};

    auto stage = [&](int buf, int k0){
        #pragma unroll
        for (int i = 0; i < SPT; i++) {
            int li = i*256 + t;
            int r = li / (BK/8), s = li % (BK/8);
            int ss = (BK==64) ? (s ^ (r & 7)) : (s ^ ((r >> 1) & 3));
            gload16(A + (size_t)(m0+r)*lda + k0 + ss*8, lA[buf] + li*8);
        }
        #pragma unroll
        for (int i = 0; i < SPT; i++) {
            int li = i*256 + t;
            int r = li / (BK/8), s = li % (BK/8);
            int ss = (BK==64) ? (s ^ (r & 7)) : (s ^ ((r >> 1) & 3));
            gload16(BT + (size_t)(n0+r)*ldb + k0 + ss*8, lB[buf] + li*8);
        }
    };

    stage(0, 0);
    __syncthreads();
    int cur = 0;
    for (int k0 = BK; k0 <= K; k0 += BK) {
        if (k0 < K) stage(cur^1, k0);             // prefetch next tile during MFMA
        #pragma unroll
        for (int kk = 0; kk < BK; kk += 32) {
            bf16x8 af[4], bfr[4];
            const int cs = (kk >> 3) + half;
            #pragma unroll
            for (int i=0;i<4;i++){
                int row = wr + i*16 + l16;
                int sl = (BK==64) ? (cs ^ (row & 7)) : (cs ^ ((row >> 1) & 3));
                af[i] = *(const bf16x8*)(lA[cur] + row*BK + sl*8);
            }
            #pragma unroll
            for (int j=0;j<4;j++){
                int row = wc + j*16 + l16;
                int sl = (BK==64) ? (cs ^ (row & 7)) : (cs ^ ((row >> 1) & 3));
                bfr[j] = *(const bf16x8*)(lB[cur] + row*BK + sl*8);
            }
            #pragma unroll
            for (int i=0;i<4;i++)
                #pragma unroll
                for (int j=0;j<4;j++)
                    acc[i][j] = __builtin_amdgcn_mfma_f32_16x16x32_bf16(af[i], bfr[j], acc[i][j], 0, 0, 0);
        }
        __syncthreads();
        cur ^= 1;
    }
    // C/D layout: col = lane&15, row = (lane>>4)*4 + q   [m89/m91 verified]
    #pragma unroll
    for (int i=0;i<4;i++)
        #pragma unroll
        for (int j=0;j<4;j++)
            #pragma unroll
            for (int q=0;q<4;q++)
                epi(m0 + wr + i*16 + half*4 + q, n0 + wc + j*16 + l16, acc[i][j][q]);
}

// ---------------- 256x128 tile, 512 threads (8 waves 4x2), BK=32 — for mm1 (K=512).
// Short-K winner [R16-measured]: 2x MFMA per barrier window vs 128-tile at 48KB LDS.
template<class Epi>
__device__ __forceinline__ void gemm_bt_tile256(const short* __restrict__ A, int lda,
                                                const short* __restrict__ BT, int ldb,
                                                int m0, int n0, int K, Epi epi)
{
    constexpr int BK = 32;
    __shared__ __align__(16) short lA[2][256*BK];
    __shared__ __align__(16) short lB[2][128*BK];
    const int t = threadIdx.x;            // 0..511
    const int lane = t & 63;
    const int w = t >> 6;                 // 0..7
    const int wr = (w >> 1) * 64;         // 0,64,128,192
    const int wc = (w & 1) * 64;          // 0,64
    const int half = lane >> 4, l16 = lane & 15;

    f32x4 acc[4][4];
    #pragma unroll
    for (int i=0;i<4;i++)
        #pragma unroll
        for (int j=0;j<4;j++)
            acc[i][j] = (f32x4){0.f,0.f,0.f,0.f};

    auto stage = [&](int buf, int k0){
        #pragma unroll
        for (int i = 0; i < 2; i++) {     // A: 256 rows x 4 slots = 1024 loads / 512 thr
            int li = i*512 + t;
            int r = li >> 2, s = li & 3;
            int ss = s ^ ((r >> 1) & 3);
            gload16(A + (size_t)(m0+r)*lda + k0 + ss*8, lA[buf] + li*8);
        }
        {                                  // B: 128 rows x 4 slots = 512 loads / 512 thr
            int li = t;
            int r = li >> 2, s = li & 3;
            int ss = s ^ ((r >> 1) & 3);
            gload16(BT + (size_t)(n0+r)*ldb + k0 + ss*8, lB[buf] + li*8);
        }
    };

    stage(0, 0);
    __syncthreads();
    int cur = 0;
    for (int k0 = BK; k0 <= K; k0 += BK) {
        if (k0 < K) stage(cur^1, k0);
        {
            bf16x8 af[4], bfr[4];
            const int cs = half;          // BK=32: slots 0..3 = k 0..31
            #pragma unroll
            for (int i=0;i<4;i++){
                int row = wr + i*16 + l16;
                af[i] = *(const bf16x8*)(lA[cur] + row*BK + (cs ^ ((row >> 1) & 3))*8);
            }
            #pragma unroll
            for (int j=0;j<4;j++){
                int row = wc + j*16 + l16;
                bfr[j] = *(const bf16x8*)(lB[cur] + row*BK + (cs ^ ((row >> 1) & 3))*8);
            }
            #pragma unroll
            for (int i=0;i<4;i++)
                #pragma unroll
                for (int j=0;j<4;j++)
                    acc[i][j] = __builtin_amdgcn_mfma_f32_16x16x32_bf16(af[i], bfr[j], acc[i][j], 0, 0, 0);
        }
        __syncthreads();
        cur ^= 1;
    }
    #pragma unroll
    for (int i=0;i<4;i++)
        #pragma unroll
        for (int j=0;j<4;j++)
            #pragma unroll
            for (int q=0;q<4;q++)
                epi(m0 + wr + i*16 + half*4 + q, n0 + wc + j*16 + l16, acc[i][j][q]);
}

// ---------------- helpers ----------------
__global__ void k_cast_node(const float* __restrict__ in, short* __restrict__ out){
    int idx = blockIdx.x*256 + threadIdx.x;
    const float4 v = ((const float4*)in)[idx];
    short4 o; o.x = f2bf(v.x); o.y = f2bf(v.y); o.z = f2bf(v.z); o.w = f2bf(v.w);
    ((short4*)out)[idx] = o;
}

__global__ void k_transpose_cast(const float* __restrict__ in, short* __restrict__ out,
                                 int R, int C){
    __shared__ short tile[64][65];
    int r0 = blockIdx.y*64, c0 = blockIdx.x*64;
    int t = threadIdx.x;
    #pragma unroll
    for (int i=0;i<16;i++){
        int lin = i*256 + t; int r = lin>>6, c = lin&63;
        tile[r][c] = f2bf(in[(size_t)(r0+r)*C + c0+c]);
    }
    __syncthreads();
    #pragma unroll
    for (int i=0;i<16;i++){
        int lin = i*256 + t; int c = lin>>6, r = lin&63;
        out[(size_t)(c0+c)*R + r0+r] = tile[r][c];
    }
}

__global__ void k_transpose_v(const short* __restrict__ values, short* __restrict__ VT){
    __shared__ short tile[64][65];
    int z = blockIdx.z;
    int c0 = blockIdx.x*64, r0 = blockIdx.y*64;
    int t = threadIdx.x;
    #pragma unroll
    for (int i=0;i<16;i++){
        int lin = i*256 + t; int r = lin>>6, c = lin&63;
        tile[r][c] = values[(size_t)(z*SEQ + r0+r)*PROJ + c0+c];
    }
    __syncthreads();
    #pragma unroll
    for (int i=0;i<16;i++){
        int lin = i*256 + t; int c = lin>>6, r = lin&63;
        VT[((size_t)z*PROJ + c0+c)*SEQ + r0+r] = tile[r][c];
    }
}

// ---------------- GEMM1 (N=2048): silu(node@w1+b1) -> gates / values
// 256x128 tile, 512 threads [R16-proven ~38us], pointer-select epilogue.
__global__ __launch_bounds__(512) void k_mm1(const short* __restrict__ nodeb,
        const short* __restrict__ w1T, const float* __restrict__ b1,
        short* __restrict__ gates, short* __restrict__ values){
    int b = blockIdx.x;                    // 512 blocks = 8 * 64
    int wg = (b & 7) * 64 + (b >> 3);      // XCD-chunked
    int n0 = (wg & 15) * 128;              // 16 n-tiles over N=2048
    int m0 = (wg >> 4) * 256;              // 32 m-tiles over 8192
    short* dst = (n0 < PROJ) ? gates : values;
    const int coff = (n0 < PROJ) ? 0 : PROJ;
    gemm_bt_tile256(nodeb, HIDN, w1T, HIDN, m0, n0, HIDN,
        [=](int row, int col, float v){
            v += b1[col];
            v = v / (1.f + __expf(-v));
            dst[(size_t)row*PROJ + (col - coff)] = f2bf(v);
        });
}

// ---------------- base-column GEMM: baseb = silu(node @ w1[:,2048:2176] + b1[2048:])
__global__ __launch_bounds__(256) void k_mmbase(const short* __restrict__ nodeb,
        const short* __restrict__ w1T, const float* __restrict__ b1,
        short* __restrict__ baseb){
    int m0 = blockIdx.x * 128;             // 64 blocks; n-tile fixed (128 cols)
    const short* BT = w1T + (size_t)(2*PROJ)*HIDN;
    gemm_bt_tile<32>(nodeb, HIDN, BT, HIDN, m0, 0, HIDN,
        [=](int row, int col, float v){
            v += b1[2*PROJ + col];
            v = v / (1.f + __expf(-v));
            baseb[(size_t)row*ATTN + col] = f2bf(v);
        });
}

// ---------------- RoPE
__global__ void k_rope2(const short* __restrict__ baseb, const float* __restrict__ msw,
                        const float* __restrict__ msb, const float* __restrict__ scaling,
                        short* __restrict__ qb, short* __restrict__ kb){
    int idx = blockIdx.x*256 + threadIdx.x;
    int d = idx & 63;
    int row = idx >> 6;
    int l = row & (SEQ-1);
    float inv = exp2f(-(float)d * (13.287712379549449f/64.f));
    float ang = (float)l * inv;
    float s = sinf(ang), c = cosf(ang);
    const short* bp = baseb + (size_t)row*ATTN;
    float b_lo = bf2f(bp[d]), b_hi = bf2f(bp[d+64]);
    float x1q = b_lo*msw[d]        + msb[d];
    float x2q = b_hi*msw[d+64]     + msb[d+64];
    float x1k = b_lo*msw[128+d]    + msb[128+d];
    float x2k = b_hi*msw[128+d+64] + msb[128+d+64];
    float sc = scaling[0];
    qb[(size_t)row*ATTN + d]    = f2bf((x1q*c - x2q*s)*sc);
    qb[(size_t)row*ATTN + d+64] = f2bf((x2q*c + x1q*s)*sc);
    kb[(size_t)row*ATTN + d]    = f2bf(x1k*c - x2k*s);
    kb[(size_t)row*ATTN + d+64] = f2bf(x2k*c + x1k*s);
}

// ---------------- QK^T + bias + exp -> UNNORMALIZED bf16 P~ + per-kvtile rowsums.
// GEMM-structured [R15-proven]: stage K+Q via swizzled global_load_lds, MFMA
// S^T=K.Q^T seeded by f32x4 bias loads, exp -> LDS transpose -> coalesced stores.
__global__ __launch_bounds__(256) void k_qksm(
        const short* __restrict__ qg, const short* __restrict__ kg,
        const float* __restrict__ bias, short* __restrict__ P,
        float* __restrict__ lsum16)
{
    __shared__ __align__(16) short smem[32768];    // 64KB: K(16K sh) | Q(16K sh); pt overlays
    __shared__ float sl[2][128];

    const int b = blockIdx.x;
    const int wg = (b & 7) * 128 + (b >> 3);       // XCD-chunked swizzle (1024 = 8*128)
    const int z  = wg >> 8;
    const int qt = (wg >> 4) & 15;
    const int kt = wg & 15;
    const int q0 = qt * 128, kv0 = kt * 128;

    const int t = threadIdx.x;
    const int lane = t & 63, w = t >> 6;
    const int wr = (w >> 1)*64, wc = (w & 1)*64;
    const int half = lane >> 4, l16 = lane & 15;

    const short* Kg = kg + ((size_t)z*SEQ + kv0)*ATTN;
    const short* Qg = qg + ((size_t)z*SEQ + q0)*ATTN;

    // stage K-tile -> smem[0:16384], Q-tile -> smem[16384:32768]; swizzle slot^(r&15)
    #pragma unroll
    for (int i = 0; i < 8; i++) {
        int li = i*256 + t;            // 0..2047
        int r = li >> 4, s = li & 15;
        int ss = s ^ (r & 15);
        gload16(Kg + (size_t)r*ATTN + ss*8, smem + li*8);
        gload16(Qg + (size_t)r*ATTN + ss*8, smem + 16384 + li*8);
    }

    // acc seeded by bias: acc[i][j] = bias[q0+col][kv0+row .. +3]  (f32x4)
    f32x4 acc[4][4];
    #pragma unroll
    for (int i=0;i<4;i++)
        #pragma unroll
        for (int j=0;j<4;j++)
            acc[i][j] = *(const f32x4*)(bias
                + ((size_t)z*SEQ + q0 + wc + j*16 + l16)*SEQ
                + kv0 + wr + i*16 + half*4);

    __syncthreads();                   // staging complete

    #pragma unroll
    for (int kk = 0; kk < 128; kk += 32) {
        const int cs = (kk >> 3) + half;
        bf16x8 af[4], bfr[4];
        #pragma unroll
        for (int i=0;i<4;i++){
            int row = wr + i*16 + l16;
            af[i] = *(const bf16x8*)(smem + row*128 + (cs ^ (row & 15))*8);
        }
        #pragma unroll
        for (int j=0;j<4;j++){
            int row = wc + j*16 + l16;
            bfr[j] = *(const bf16x8*)(smem + 16384 + row*128 + (cs ^ (row & 15))*8);
        }
        #pragma unroll
        for (int i=0;i<4;i++)
            #pragma unroll
            for (int j=0;j<4;j++)
                acc[i][j] = __builtin_amdgcn_mfma_f32_16x16x32_bf16(af[i], bfr[j], acc[i][j], 0, 0, 0);
    }

    __syncthreads();                   // all ds_reads done; smem reusable as pt

    // exp + transpose into pt[q][kv] (stride 136 shorts, 8B-aligned writes)
    short* pt = smem;                  // [128][136] = 17408 shorts, fits 32768
    float tsum[4];
    #pragma unroll
    for (int j=0;j<4;j++){
        int col = wc + j*16 + l16;     // q local
        float sj = 0.f;
        #pragma unroll
        for (int i=0;i<4;i++){
            float p0=__expf(acc[i][j][0]), p1=__expf(acc[i][j][1]);
            float p2=__expf(acc[i][j][2]), p3=__expf(acc[i][j][3]);
            sj += p0+p1+p2+p3;
            short4 pv; pv.x=f2bf(p0); pv.y=f2bf(p1); pv.z=f2bf(p2); pv.w=f2bf(p3);
            *(short4*)(pt + col*136 + wr + i*16 + half*4) = pv;   // 8B write, 4 consec kv
        }
        tsum[j] = sj;
    }
    // reduce rows over half-groups -> per-(wave,col) 64-kv sums
    #pragma unroll
    for (int j=0;j<4;j++){
        tsum[j] += __shfl_xor(tsum[j],16,64);
        tsum[j] += __shfl_xor(tsum[j],32,64);
    }
    if (half==0){
        #pragma unroll
        for (int j=0;j<4;j++) sl[wr>>6][wc + j*16 + l16] = tsum[j];
    }
    __syncthreads();

    // coalesced P~ store: 2048 stores = 128 q x 16 groups of 8 bf16
    short* Pp = P + ((size_t)z*SEQ + q0)*SEQ + kv0;
    #pragma unroll
    for (int i=0;i<8;i++){
        int idx = i*256 + t;           // 0..2047
        int q = idx >> 4, g = idx & 15;
        *(bf16x8*)(Pp + (size_t)q*SEQ + g*8) = *(const bf16x8*)(pt + q*136 + g*8);
    }
    if (t < 128)
        lsum16[(size_t)kt*ROWS + (size_t)z*SEQ + q0 + t] = sl[0][t] + sl[1][t];
}

// ---------------- combine per-kvtile partials -> 1/rowsum
__global__ void k_combine(const float* __restrict__ lsum16, float* __restrict__ linv){
    int r = blockIdx.x*256 + threadIdx.x;
    float s = 0.f;
    #pragma unroll
    for (int kt=0; kt<16; kt++) s += lsum16[(size_t)kt*ROWS + r];
    linv[r] = 1.f/s;
}

// ---------------- PV: a2 = (P~ @ V) * linv * gates  (bf16 out), BK=64
__global__ __launch_bounds__(256) void k_pv2(const short* __restrict__ P,
        const short* __restrict__ VT, const short* __restrict__ gates,
        const float* __restrict__ linv, short* __restrict__ a2){
    int b = blockIdx.x;
    int wg = (b & 7) * 64 + (b >> 3);
    int xx = wg & 7, yy = (wg >> 3) & 15, z = wg >> 7;
    const short* A = P  + (size_t)z*SEQ*SEQ;
    const short* B = VT + (size_t)z*PROJ*SEQ;
    int n0 = xx*128, m0 = yy*128;
    gemm_bt_tile<64>(A, SEQ, B, SEQ, m0, n0, SEQ,
        [=](int r, int c, float v){
            size_t ri = (size_t)z*SEQ + r;
            size_t gi = ri*PROJ + c;
            a2[gi] = f2bf(v * linv[ri] * bf2f(gates[gi]));
        });
}

// ---------------- GEMM2: out = a2 @ w2 + b2  (f32 out), BK=64
__global__ __launch_bounds__(256) void k_mm2(const short* __restrict__ a2,
        const short* __restrict__ w2T, const float* __restrict__ b2,
        float* __restrict__ out){
    int b = blockIdx.x;
    int wg = (b & 7) * 32 + (b >> 3);
    int n0 = (wg & 3)*128, m0 = (wg >> 2)*128;
    gemm_bt_tile<64>(a2, PROJ, w2T, PROJ, m0, n0, PROJ,
        [=](int r, int c, float v){
            out[(size_t)r*HIDN + c] = v + b2[c];
        });
}

extern "C" void kernel_launch(void* const* d_in, const int* in_sizes, int n_in,
                              void* d_out, int out_size, void* d_ws, size_t ws_size,
                              hipStream_t stream) {
    const float* node    = (const float*)d_in[0];
    const float* bias    = (const float*)d_in[1];
    const float* scaling = (const float*)d_in[2];
    const float* w1      = (const float*)d_in[3];
    const float* b1      = (const float*)d_in[4];
    const float* msw     = (const float*)d_in[5];
    const float* msb     = (const float*)d_in[6];
    const float* w2      = (const float*)d_in[7];
    const float* b2      = (const float*)d_in[8];
    float* out = (float*)d_out;

    char* p = (char*)d_ws;
    auto alloc = [&](size_t bytes){ char* r = p; p += (bytes + 255) & ~(size_t)255; return r; };
    short* nodeb  = (short*)alloc((size_t)ROWS*HIDN*2);
    short* w1T    = (short*)alloc((size_t)N1*HIDN*2);
    short* w2T    = (short*)alloc((size_t)HIDN*PROJ*2);
    short* gates  = (short*)alloc((size_t)ROWS*PROJ*2);
    short* values = (short*)alloc((size_t)ROWS*PROJ*2);
    short* VT     = (short*)alloc((size_t)BATCH*PROJ*SEQ*2);
    short* baseb  = (short*)alloc((size_t)ROWS*ATTN*2);
    short* qb     = (short*)alloc((size_t)ROWS*ATTN*2);
    short* kb     = (short*)alloc((size_t)ROWS*ATTN*2);
    short* Pbuf   = (short*)alloc((size_t)BATCH*SEQ*SEQ*2);
    float* lsum16 = (float*)alloc((size_t)16*ROWS*4);
    float* linv   = (float*)alloc((size_t)ROWS*4);
    short* a2buf  = (short*)alloc((size_t)ROWS*PROJ*2);

    k_cast_node<<<ROWS*HIDN/1024, 256, 0, stream>>>(node, nodeb);
    k_transpose_cast<<<dim3(N1/64, HIDN/64), 256, 0, stream>>>(w1, w1T, HIDN, N1);
    k_transpose_cast<<<dim3(HIDN/64, PROJ/64), 256, 0, stream>>>(w2, w2T, PROJ, HIDN);
    // 1) gva = silu(node@w1+b1): N=2048 main GEMM (256x128, BK=32) + base columns
    k_mm1<<<16*(ROWS/256), 512, 0, stream>>>(nodeb, w1T, b1, gates, values);
    k_mmbase<<<ROWS/128, 256, 0, stream>>>(nodeb, w1T, b1, baseb);
    // transpose values for PV B^T layout
    k_transpose_v<<<dim3(PROJ/64, SEQ/64, BATCH), 256, 0, stream>>>(values, VT);
    // 2) rope
    k_rope2<<<ROWS*64/256, 256, 0, stream>>>(baseb, msw, msb, scaling, qb, kb);
    // 3) GEMM-structured qk^T + bias + exp -> P~ + per-kvtile partial sums
    k_qksm<<<16*16*BATCH, 256, 0, stream>>>(qb, kb, bias, Pbuf, lsum16);
    k_combine<<<ROWS/256, 256, 0, stream>>>(lsum16, linv);
    // 3c) a2 = (P~@V)*linv*gates
    k_pv2<<<(PROJ/128)*(SEQ/128)*BATCH, 256, 0, stream>>>(Pbuf, VT, gates, linv, a2buf);
    // 4) out = a2@w2 + b2
    k_mm2<<<(HIDN/128)*(ROWS/128), 256, 0, stream>>>(a2buf, w2T, b2, out);
}